// Round 11
// baseline (451.803 us; speedup 1.0000x reference)
//
#include <hip/hip_runtime.h>

typedef int int32x4 __attribute__((ext_vector_type(4)));
typedef int int32x16 __attribute__((ext_vector_type(16)));

// ---------------------------------------------------------------------------
// K-major blocked layout (BK=128 B, 16 KiB blocks):
//   block id = rowblk*(K/128) + kblk; in-block byte = ch*2048 + row*16 + b
//   (ch = which 16-B K-chunk, row = 0..127, b = 0..15)
// Frag reads hit 256 CONTIGUOUS bytes per 16-lane quarter -> 2 words/bank,
// zero conflicts by construction (the model that explains r7's measured 0).
// Staging stays a contiguous 16 KB copy (rule #21). No XOR swizzle anywhere.
// ---------------------------------------------------------------------------

// fused: y=0 maxabs(W1), y=1 maxabs(W2), y=2 quant x -> K-major blocked int8
__global__ void prep_kernel(const float* __restrict__ W1,
                            const float* __restrict__ W2,
                            const float* __restrict__ x, int n4,
                            int Kx, int kshiftx,
                            const float* __restrict__ s1,
                            unsigned* __restrict__ mx, int* __restrict__ xq) {
    int i0 = blockIdx.x * blockDim.x + threadIdx.x;
    int stride = gridDim.x * blockDim.x;
    if (blockIdx.y < 2) {
        const float4* x4 = (const float4*)(blockIdx.y ? W2 : W1);
        float m = 0.f;
        for (int j = i0; j < n4; j += stride) {
            float4 v = x4[j];
            m = fmaxf(m, fmaxf(fmaxf(fabsf(v.x), fabsf(v.y)),
                               fmaxf(fabsf(v.z), fabsf(v.w))));
        }
#pragma unroll
        for (int off = 32; off; off >>= 1)
            m = fmaxf(m, __shfl_down(m, off, 64));
        __shared__ float wm[4];
        int ln = threadIdx.x & 63, wv = threadIdx.x >> 6;
        if (ln == 0) wm[wv] = m;
        __syncthreads();
        if (threadIdx.x == 0) {
            float bm = fmaxf(fmaxf(wm[0], wm[1]), fmaxf(wm[2], wm[3]));
            atomicMax(mx + blockIdx.y, __float_as_uint(bm));  // nonneg: bit order ok
        }
    } else {
        float s = s1[0];
        for (int o = i0; o < n4; o += stride) {
            int blk = o >> 12, i = o & 4095;
            int ch = i >> 9, row = (i >> 2) & 127, w = i & 3;
            int rowblk = blk >> kshiftx, kblk = blk & ((1 << kshiftx) - 1);
            long srcoff = (long)(rowblk * 128 + row) * Kx + (kblk << 7) + (ch << 4) + (w << 2);
            float4 f = *(const float4*)(x + srcoff);
            int a = (int)fminf(fmaxf(rintf(f.x / s), -8.f), 7.f);
            int b = (int)fminf(fmaxf(rintf(f.y / s), -8.f), 7.f);
            int c = (int)fminf(fmaxf(rintf(f.z / s), -8.f), 7.f);
            int d = (int)fminf(fmaxf(rintf(f.w / s), -8.f), 7.f);
            xq[o] = (a & 255) | ((b & 255) << 8) | ((c & 255) << 16) | ((d & 255) << 24);
        }
    }
}

// merged W-quant: y=0 -> W1 (K=K1), y=1 -> W2 (K=K2); scale = mx[y]/7
__global__ void quantW_kernel(const float* __restrict__ W1,
                              const float* __restrict__ W2, int n4,
                              int K1, int ks1, int K2, int ks2,
                              const unsigned* __restrict__ mx,
                              int* __restrict__ w1q, int* __restrict__ w2q) {
    const int y = blockIdx.y;
    const float* src = y ? W2 : W1;
    int* out = y ? w2q : w1q;
    const int K = y ? K2 : K1;
    const int kshift = y ? ks2 : ks1;
    float s = __uint_as_float(mx[y]) / 7.0f;
    int i0 = blockIdx.x * blockDim.x + threadIdx.x;
    int stride = gridDim.x * blockDim.x;
    for (int o = i0; o < n4; o += stride) {
        int blk = o >> 12, i = o & 4095;
        int ch = i >> 9, row = (i >> 2) & 127, w = i & 3;
        int rowblk = blk >> kshift, kblk = blk & ((1 << kshift) - 1);
        long srcoff = (long)(rowblk * 128 + row) * K + (kblk << 7) + (ch << 4) + (w << 2);
        float4 f = *(const float4*)(src + srcoff);
        int a = (int)fminf(fmaxf(rintf(f.x / s), -8.f), 7.f);
        int b = (int)fminf(fmaxf(rintf(f.y / s), -8.f), 7.f);
        int c = (int)fminf(fmaxf(rintf(f.z / s), -8.f), 7.f);
        int d = (int)fminf(fmaxf(rintf(f.w / s), -8.f), 7.f);
        out[o] = (a & 255) | ((b & 255) << 8) | ((c & 255) << 16) | ((d & 255) << 24);
    }
}

// ---------------------------------------------------------------------------
// int8 GEMM, C[m,n] = sum_k A[m,k]*B[n,k], operands in K-major blocked layout.
// r7 skeleton (best measured: single-buffer 32 KiB, 2 barriers/K-tile,
// contiguous staging, ~3.3 blocks/CU) retargeted to mfma_i32_32x32x32_i8:
// 4 waves (2x2), wave tile 64x64 = 2x2 frags x 4 K-steps = 16 MFMA/K-tile
// (half the issue slots of r7, +12% pipe ceiling). Frag A (fm,ks):
// 16 B at lds[ch=2ks+(ln>>5)][row=wr*64+fm*32+(ln&31)] -> contiguous
// 256 B per 16-lane quarter = conflict-free. C/D mapping verified in r5:
// col = lane&31, row = 4*(lane>>5) + (reg&3) + 8*(reg>>2).
// ---------------------------------------------------------------------------
template <bool FIRST>
__global__ __launch_bounds__(256, 2)
void gemm_i8_kernel(const char* __restrict__ A, const char* __restrict__ B,
                    int N, int nkt,
                    const float* __restrict__ sa_ptr,
                    const float* __restrict__ wmax_ptr,
                    const float* __restrict__ bias,
                    const float* __restrict__ s2_ptr,
                    char* __restrict__ out8, float* __restrict__ outf) {
    __shared__ __align__(16) char lA[128 * 128];  // [ch 8][row 128][16 B]
    __shared__ __align__(16) char lB[128 * 128];

    const int tid = threadIdx.x;
    const int wv = tid >> 6, ln = tid & 63;
    const int l31 = ln & 31, hi5 = ln >> 5;
    const int wr = wv >> 1, wc = wv & 1;

    int32x16 acc[2][2] = {};

    const char* pa = A + ((size_t)blockIdx.y * nkt << 14);
    const char* pb = B + ((size_t)blockIdx.x * nkt << 14);

    for (int kt = 0; kt < nkt; ++kt) {
        // ---- stage: contiguous 16 KB copy per operand ----
#pragma unroll
        for (int r = 0; r < 4; ++r) {
            int off = (r * 256 + tid) * 16;
            int lbase = (r * 256 + wv * 64) * 16;  // wave-uniform base (+ln*16 HW)
            __builtin_amdgcn_global_load_lds(
                (const __attribute__((address_space(1))) void*)(pa + off),
                (__attribute__((address_space(3))) void*)(lA + lbase), 16, 0, 0);
            __builtin_amdgcn_global_load_lds(
                (const __attribute__((address_space(1))) void*)(pb + off),
                (__attribute__((address_space(3))) void*)(lB + lbase), 16, 0, 0);
        }
        pa += 16384;
        pb += 16384;
        __syncthreads();

        // ---- LDS -> fragments (K-major; contiguous per 16-lane quarter) ----
        int32x4 af[2][4], bf[2][4];
#pragma unroll
        for (int fm = 0; fm < 2; ++fm)
#pragma unroll
            for (int ks = 0; ks < 4; ++ks) {
                int row = wr * 64 + fm * 32 + l31;
                int ch = ks * 2 + hi5;
                af[fm][ks] = *(const int32x4*)(lA + ch * 2048 + row * 16);
            }
#pragma unroll
        for (int fn = 0; fn < 2; ++fn)
#pragma unroll
            for (int ks = 0; ks < 4; ++ks) {
                int col = wc * 64 + fn * 32 + l31;
                int ch = ks * 2 + hi5;
                bf[fn][ks] = *(const int32x4*)(lB + ch * 2048 + col * 16);
            }

        // ---- MFMA: 16 x 32x32x32 i8 ----
        __builtin_amdgcn_s_setprio(1);
#pragma unroll
        for (int ks = 0; ks < 4; ++ks)
#pragma unroll
            for (int fm = 0; fm < 2; ++fm)
#pragma unroll
                for (int fn = 0; fn < 2; ++fn)
                    acc[fm][fn] = __builtin_amdgcn_mfma_i32_32x32x32_i8(
                        af[fm][ks], bf[fn][ks], acc[fm][fn], 0, 0, 0);
        __builtin_amdgcn_s_setprio(0);
        __syncthreads();
    }

    // ---- epilogue (r5-verified 32x32 C/D mapping) ----
    float sa = sa_ptr[0];
    float sw = __uint_as_float(((const unsigned*)wmax_ptr)[0]) / 7.0f;
    float sab = sa * sw;
    float s2v = FIRST ? s2_ptr[0] : 0.f;

    char* hblk = FIRST ? out8 + (((size_t)blockIdx.y * gridDim.x + blockIdx.x) << 14)
                       : nullptr;

#pragma unroll
    for (int fn = 0; fn < 2; ++fn) {
        int lc = wc * 64 + fn * 32 + l31;                // local col 0..127
        long col = (long)blockIdx.x * 128 + lc;          // global col
        float bq = rintf(bias[col] / sab) * sab;         // Int32Bias fake-quant
#pragma unroll
        for (int fm = 0; fm < 2; ++fm) {
            int lr0 = wr * 64 + fm * 32 + (hi5 << 2);
#pragma unroll
            for (int reg = 0; reg < 16; ++reg) {
                int lr = lr0 + (reg & 3) + 8 * (reg >> 2);
                float h = sab * (float)acc[fm][fn][reg] + bq;
                if constexpr (FIRST) {
                    h = fmaxf(h, 0.f);
                    float qv = fminf(fmaxf(rintf(h / s2v), 0.f), 15.f);
                    // hq in K-major blocked layout for GEMM2
                    hblk[(lc >> 4) * 2048 + lr * 16 + (lc & 15)] = (char)(int)qv;
                } else {
                    outf[((long)blockIdx.y * 128 + lr) * N + col] = h;
                }
            }
        }
    }
}

// ---------------------------------------------------------------------------
// launch
// ---------------------------------------------------------------------------
extern "C" void kernel_launch(void* const* d_in, const int* in_sizes, int n_in,
                              void* d_out, int out_size, void* d_ws, size_t ws_size,
                              hipStream_t stream) {
    const float* x  = (const float*)d_in[0];   // [4,2048,2048] -> [8192,2048]
    const float* W1 = (const float*)d_in[1];   // [8192,2048]
    const float* b1 = (const float*)d_in[2];   // [8192]
    const float* W2 = (const float*)d_in[3];   // [2048,8192]
    const float* b2 = (const float*)d_in[4];   // [2048]
    const float* s1 = (const float*)d_in[5];
    const float* s2 = (const float*)d_in[6];

    const int M = 8192, D = 2048, F = 8192;

    char* ws = (char*)d_ws;
    unsigned* mx = (unsigned*)ws;          // mx[0]=maxabs(W1), mx[1]=maxabs(W2)
    char* xq  = ws + 256;                  // [M/128][D/128][16384] K-major
    char* w1q = xq + (size_t)M * D;        // [F/128][D/128][16384]
    char* w2q = w1q + (size_t)F * D;       // [D/128][F/128][16384]
    char* hq  = w2q + (size_t)D * F;       // [M/128][F/128][16384]

    hipMemsetAsync(d_ws, 0, 8, stream);    // zero the maxabs slots

    const int n4 = (F * D) >> 2;           // == (M*D)>>2, same for all three
    // y=0: maxabs W1, y=1: maxabs W2, y=2: quant x (independent of scales)
    prep_kernel<<<dim3(2048, 3), 256, 0, stream>>>(
        W1, W2, x, n4, D, 4, s1, mx, (int*)xq);

    // y=0: quant W1 (K=D, kshift=4), y=1: quant W2 (K=F, kshift=6)
    quantW_kernel<<<dim3(2048, 2), 256, 0, stream>>>(
        W1, W2, n4, D, 4, F, 6, mx, (int*)w1q, (int*)w2q);

    // h_q = clip(round(relu(x_q W1_q^T + b1_q)/s2),0,15) -> K-major blocked
    gemm_i8_kernel<true><<<dim3(F / 128, M / 128), 256, 0, stream>>>(
        xq, w1q, F, D / 128, s1, (const float*)mx, b1, s2, hq, nullptr);

    // out = s2*sw2 * (h_int W2_int^T) + b2_q
    gemm_i8_kernel<false><<<dim3(D / 128, M / 128), 256, 0, stream>>>(
        hq, w2q, D, F / 128, s2, (const float*)(mx + 1), b2, nullptr, nullptr,
        (float*)d_out);
}

// Round 12
// 363.644 us; speedup vs baseline: 1.2424x; 1.2424x over previous
//
#include <hip/hip_runtime.h>

typedef int int32x4 __attribute__((ext_vector_type(4)));

// ---------------------------------------------------------------------------
// Blocked-preswizzled operand layout (r7, verified):
//   16384-B blocks, blk = rowblk*(K/128)+kblk
//   stored[row][c] = orig[row][c ^ (row&7)]  (row 0..127, c = 16-B chunk 0..7)
// = the exact LDS image the GEMM builds, so staging is a contiguous 16 KB
// copy (rule #21) and the swizzled ds_read_b128 pattern measures 0 conflicts.
// ---------------------------------------------------------------------------

// fused prep: y=0 maxabs(W1), y=1 maxabs(W2), y=2 quant x -> blocked int8
__global__ void prep_kernel(const float* __restrict__ W1,
                            const float* __restrict__ W2,
                            const float* __restrict__ x, int n4,
                            int Kx, int kshiftx,
                            const float* __restrict__ s1,
                            unsigned* __restrict__ mx, int* __restrict__ xq) {
    int i0 = blockIdx.x * blockDim.x + threadIdx.x;
    int stride = gridDim.x * blockDim.x;
    if (blockIdx.y < 2) {
        const float4* x4 = (const float4*)(blockIdx.y ? W2 : W1);
        float m = 0.f;
        for (int j = i0; j < n4; j += stride) {
            float4 v = x4[j];
            m = fmaxf(m, fmaxf(fmaxf(fabsf(v.x), fabsf(v.y)),
                               fmaxf(fabsf(v.z), fabsf(v.w))));
        }
#pragma unroll
        for (int off = 32; off; off >>= 1)
            m = fmaxf(m, __shfl_down(m, off, 64));
        __shared__ float wm[4];
        int ln = threadIdx.x & 63, wv = threadIdx.x >> 6;
        if (ln == 0) wm[wv] = m;
        __syncthreads();
        if (threadIdx.x == 0) {
            float bm = fmaxf(fmaxf(wm[0], wm[1]), fmaxf(wm[2], wm[3]));
            atomicMax(mx + blockIdx.y, __float_as_uint(bm));  // nonneg: bit order ok
        }
    } else {
        float s = s1[0];
        for (int o = i0; o < n4; o += stride) {
            int blk = o >> 12;            // 4096 int-groups per 16 KB block
            int i = o & 4095;
            int row = i >> 5;             // 32 groups per 128-B row
            int c = (i >> 2) & 7;         // stored 16-B chunk
            int b4 = i & 3;               // float4 within chunk
            int rowblk = blk >> kshiftx;
            int kblk = blk & ((1 << kshiftx) - 1);
            int co = c ^ (row & 7);       // original chunk (inverse swizzle)
            long srcoff = (long)(rowblk * 128 + row) * Kx + (kblk << 7) + (co << 4) + (b4 << 2);
            float4 f = *(const float4*)(x + srcoff);
            int a = (int)fminf(fmaxf(rintf(f.x / s), -8.f), 7.f);
            int b = (int)fminf(fmaxf(rintf(f.y / s), -8.f), 7.f);
            int cc = (int)fminf(fmaxf(rintf(f.z / s), -8.f), 7.f);
            int d = (int)fminf(fmaxf(rintf(f.w / s), -8.f), 7.f);
            xq[o] = (a & 255) | ((b & 255) << 8) | ((cc & 255) << 16) | ((d & 255) << 24);
        }
    }
}

// merged W-quant: y=0 -> W1 (K=K1), y=1 -> W2 (K=K2); scale = mx[y]/7
__global__ void quantW_kernel(const float* __restrict__ W1,
                              const float* __restrict__ W2, int n4,
                              int K1, int ks1, int K2, int ks2,
                              const unsigned* __restrict__ mx,
                              int* __restrict__ w1q, int* __restrict__ w2q) {
    const int y = blockIdx.y;
    const float* src = y ? W2 : W1;
    int* out = y ? w2q : w1q;
    const int K = y ? K2 : K1;
    const int kshift = y ? ks2 : ks1;
    float s = __uint_as_float(mx[y]) / 7.0f;
    int i0 = blockIdx.x * blockDim.x + threadIdx.x;
    int stride = gridDim.x * blockDim.x;
    for (int o = i0; o < n4; o += stride) {
        int blk = o >> 12;
        int i = o & 4095;
        int row = i >> 5;
        int c = (i >> 2) & 7;
        int b4 = i & 3;
        int rowblk = blk >> kshift;
        int kblk = blk & ((1 << kshift) - 1);
        int co = c ^ (row & 7);
        long srcoff = (long)(rowblk * 128 + row) * K + (kblk << 7) + (co << 4) + (b4 << 2);
        float4 f = *(const float4*)(src + srcoff);
        int a = (int)fminf(fmaxf(rintf(f.x / s), -8.f), 7.f);
        int b = (int)fminf(fmaxf(rintf(f.y / s), -8.f), 7.f);
        int cc = (int)fminf(fmaxf(rintf(f.z / s), -8.f), 7.f);
        int d = (int)fminf(fmaxf(rintf(f.w / s), -8.f), 7.f);
        out[o] = (a & 255) | ((b & 255) << 8) | ((cc & 255) << 16) | ((d & 255) << 24);
    }
}

// ---------------------------------------------------------------------------
// int8 GEMM (r7 verbatim — best measured: 151.5 µs, MfmaUtil 42%, 0 bank
// conflicts, ~3.3 blocks/CU). C[m,n] = sum_k A[m,k]*B[n,k], operands in
// blocked-preswizzled layout. 128x128 tile, BK=128 B, 4 waves (2x2),
// single-buffer 32 KiB LDS, 16x16x64 MFMA, contiguous 16 KB staging,
// 2 barriers/K-tile. FIRST epilogue writes hq in the same blocked layout.
// ---------------------------------------------------------------------------
template <bool FIRST>
__global__ __launch_bounds__(256, 2)
void gemm_i8_kernel(const char* __restrict__ A, const char* __restrict__ B,
                    int N, int nkt,
                    const float* __restrict__ sa_ptr,
                    const float* __restrict__ wmax_ptr,
                    const float* __restrict__ bias,
                    const float* __restrict__ s2_ptr,
                    char* __restrict__ out8, float* __restrict__ outf) {
    __shared__ __align__(16) char lA[128 * 128];
    __shared__ __align__(16) char lB[128 * 128];

    const int tid = threadIdx.x;
    const int wv = tid >> 6, ln = tid & 63;
    const int lnlo = ln & 15, lnhi = ln >> 4;
    const int wr = wv >> 1, wc = wv & 1;

    int32x4 acc[4][4] = {};

    // blocked operand bases: block index = rowblk*nkt + kt
    const char* pa = A + ((size_t)blockIdx.y * nkt << 14);
    const char* pb = B + ((size_t)blockIdx.x * nkt << 14);

    for (int kt = 0; kt < nkt; ++kt) {
        // ---- stage: contiguous 16 KB copy per operand ----
#pragma unroll
        for (int r = 0; r < 4; ++r) {
            int off = (r * 256 + tid) * 16;
            int lbase = (r * 256 + wv * 64) * 16;  // wave-uniform base (+ln*16 by HW)
            __builtin_amdgcn_global_load_lds(
                (const __attribute__((address_space(1))) void*)(pa + off),
                (__attribute__((address_space(3))) void*)(lA + lbase), 16, 0, 0);
            __builtin_amdgcn_global_load_lds(
                (const __attribute__((address_space(1))) void*)(pb + off),
                (__attribute__((address_space(3))) void*)(lB + lbase), 16, 0, 0);
        }
        pa += 16384;
        pb += 16384;
        __syncthreads();

        // ---- LDS -> fragments (swizzled read, measured 0 conflicts) ----
        int32x4 af[4][2], bf[4][2];
#pragma unroll
        for (int mf = 0; mf < 4; ++mf)
#pragma unroll
            for (int kk = 0; kk < 2; ++kk) {
                int row = wr * 64 + mf * 16 + lnlo;
                int ch = kk * 4 + lnhi;
                af[mf][kk] = *(const int32x4*)(lA + row * 128 + ((ch ^ (row & 7)) * 16));
            }
#pragma unroll
        for (int nf = 0; nf < 4; ++nf)
#pragma unroll
            for (int kk = 0; kk < 2; ++kk) {
                int col = wc * 64 + nf * 16 + lnlo;
                int ch = kk * 4 + lnhi;
                bf[nf][kk] = *(const int32x4*)(lB + col * 128 + ((ch ^ (col & 7)) * 16));
            }

        // ---- MFMA ----
#pragma unroll
        for (int kk = 0; kk < 2; ++kk)
#pragma unroll
            for (int mf = 0; mf < 4; ++mf)
#pragma unroll
                for (int nf = 0; nf < 4; ++nf)
                    acc[mf][nf] = __builtin_amdgcn_mfma_i32_16x16x64_i8(
                        af[mf][kk], bf[nf][kk], acc[mf][nf], 0, 0, 0);
        __syncthreads();
    }

    // ---- epilogue ----
    float sa = sa_ptr[0];
    float sw = wmax_ptr[0] / 7.0f;  // weight_scale (bits of maxabs as float)
    float sab = sa * sw;
    float s2v = FIRST ? s2_ptr[0] : 0.f;

    // hq destination block (GEMM1): [mblk][fblk] = [blockIdx.y][blockIdx.x]
    char* hblk = FIRST ? out8 + (((size_t)blockIdx.y * gridDim.x + blockIdx.x) << 14)
                       : nullptr;

#pragma unroll
    for (int nf = 0; nf < 4; ++nf) {
        int lc = wc * 64 + nf * 16 + lnlo;               // local col 0..127
        long col = (long)blockIdx.x * 128 + lc;          // global col
        float bq = rintf(bias[col] / sab) * sab;         // Int32Bias fake-quant
#pragma unroll
        for (int mf = 0; mf < 4; ++mf) {
            int lr0 = wr * 64 + mf * 16 + (lnhi << 2);   // local row base
#pragma unroll
            for (int i = 0; i < 4; ++i) {
                int lr = lr0 + i;
                float h = sab * (float)acc[mf][nf][i] + bq;
                if constexpr (FIRST) {
                    h = fmaxf(h, 0.f);
                    float qv = fminf(fmaxf(rintf(h / s2v), 0.f), 15.f);
                    // blocked-preswizzled store: stored[lr][c]=orig[lr][c^(lr&7)]
                    hblk[lr * 128 + (((lc >> 4) ^ (lr & 7)) << 4) + (lc & 15)] =
                        (char)(int)qv;
                } else {
                    outf[((long)blockIdx.y * 128 + lr) * N + col] = h;
                }
            }
        }
    }
}

// ---------------------------------------------------------------------------
// launch
// ---------------------------------------------------------------------------
extern "C" void kernel_launch(void* const* d_in, const int* in_sizes, int n_in,
                              void* d_out, int out_size, void* d_ws, size_t ws_size,
                              hipStream_t stream) {
    const float* x  = (const float*)d_in[0];   // [4,2048,2048] -> [8192,2048]
    const float* W1 = (const float*)d_in[1];   // [8192,2048]
    const float* b1 = (const float*)d_in[2];   // [8192]
    const float* W2 = (const float*)d_in[3];   // [2048,8192]
    const float* b2 = (const float*)d_in[4];   // [2048]
    const float* s1 = (const float*)d_in[5];
    const float* s2 = (const float*)d_in[6];

    const int M = 8192, D = 2048, F = 8192;

    char* ws = (char*)d_ws;
    unsigned* mx = (unsigned*)ws;          // mx[0]=maxabs(W1), mx[1]=maxabs(W2)
    char* xq  = ws + 256;                  // [M/128][D/128][16384]
    char* w1q = xq + (size_t)M * D;        // [F/128][D/128][16384]
    char* w2q = w1q + (size_t)F * D;       // [D/128][F/128][16384]
    char* hq  = w2q + (size_t)D * F;       // [M/128][F/128][16384]

    hipMemsetAsync(d_ws, 0, 8, stream);    // zero the maxabs slots

    const int n4 = (F * D) >> 2;           // == (M*D)>>2 == (D*F)>>2
    // y=0: maxabs W1, y=1: maxabs W2, y=2: quant x (needs only s1)
    prep_kernel<<<dim3(2048, 3), 256, 0, stream>>>(
        W1, W2, x, n4, D, 4, s1, mx, (int*)xq);

    // y=0: quant W1 (K=D, kshift=4), y=1: quant W2 (K=F, kshift=6)
    quantW_kernel<<<dim3(2048, 2), 256, 0, stream>>>(
        W1, W2, n4, D, 4, F, 6, mx, (int*)w1q, (int*)w2q);

    // h_q = clip(round(relu(x_q W1_q^T + b1_q)/s2),0,15) -> blocked int8
    gemm_i8_kernel<true><<<dim3(F / 128, M / 128), 256, 0, stream>>>(
        xq, w1q, F, D / 128, s1, (const float*)mx, b1, s2, hq, nullptr);

    // out = s2*sw2 * (h_int W2_int^T) + b2_q
    gemm_i8_kernel<false><<<dim3(D / 128, M / 128), 256, 0, stream>>>(
        hq, w2q, D, F / 128, s2, (const float*)(mx + 1), b2, nullptr, nullptr,
        (float*)d_out);
}